// Round 7
// baseline (2353.358 us; speedup 1.0000x reference)
//
#include <hip/hip_runtime.h>
#include <math.h>

#define B_ 1024
#define T_ 128
#define H_ 2048
#define C_ 10

typedef __bf16 bf16_t;
typedef __bf16 bf16x8 __attribute__((ext_vector_type(8)));
typedef __bf16 bf16x4 __attribute__((ext_vector_type(4)));
typedef float f32x4 __attribute__((ext_vector_type(4)));

// Static device storage: bf16 h ping-pong (8 MB), bf16 W_hh in MFMA
// fragment-linear order (8 MB), per-(t,bm) readiness counters.
__device__ __align__(16) bf16_t g_hb[2][(size_t)B_ * H_];
// g_whhB[(((bn*32 + c)*8) + (wnh*4 + j*2 + cc))*512 + lane*8 + e]
//   = W_hh[k][n], n = bn*64+wnh*32+j*16+(lane&15), k = c*64+cc*32+(lane>>4)*8+e
__device__ __align__(16) bf16_t g_whhB[(size_t)H_ * H_];
__device__ int g_cnt[T_ * 8];   // [t][bm]; t=0 seeded to 32 by rnn_init

// AUX: cache policy. 0 = default; 1 = sc0 (force L1 miss -> read XCD L2).
template <int AUX>
__device__ __forceinline__ void gload16(const bf16_t* g, bf16_t* l) {
    __builtin_amdgcn_global_load_lds(
        (const __attribute__((address_space(1))) void*)g,
        (__attribute__((address_space(3))) void*)l, 16, 0, AUX);
}

// Counted-vmcnt barrier: retire oldest pipeline stage without draining.
template <int VM>
__device__ __forceinline__ void wait_vm_barrier() {
    asm volatile("s_waitcnt vmcnt(%0)\n\ts_barrier" :: "n"(VM) : "memory");
}

// One-time: build g_whhB (transpose + bf16 + fragment-linear reorder).
// Block = one (bn, c) 64n x 64k tile. Input rows coalesced; output
// contiguous 8 KB per block; LDS pad-65 keeps read conflicts <= 2-way.
__global__ __launch_bounds__(256) void prep_whhB(const float* __restrict__ Whh) {
    __shared__ float tld[64 * 65];   // [k][n]
    const int c  = blockIdx.x;       // K chunk 0..31
    const int bn = blockIdx.y;       // 64-col N tile 0..31
    const int t  = threadIdx.x;
#pragma unroll
    for (int q = 0; q < 4; ++q) {
        const int idx = t + q * 256;         // f32x4 unit 0..1023
        const int kk  = idx >> 4;
        const int n4  = (idx & 15) * 4;
        f32x4 v = *(const f32x4*)(Whh + (size_t)(c * 64 + kk) * H_ + bn * 64 + n4);
        tld[kk * 65 + n4 + 0] = v[0]; tld[kk * 65 + n4 + 1] = v[1];
        tld[kk * 65 + n4 + 2] = v[2]; tld[kk * 65 + n4 + 3] = v[3];
    }
    __syncthreads();
    const int lane_o = t & 63, b8b = t >> 6;
    const int fro = lane_o & 15, fqo = lane_o >> 4;
    const size_t obase = ((size_t)(bn * 32 + c) * 8) * 512;
#pragma unroll
    for (int h = 0; h < 2; ++h) {
        const int b8  = b8b + h * 4;          // wnh*4 + j*2 + cc
        const int wnh = b8 >> 2, j = (b8 >> 1) & 1, cc = b8 & 1;
        const int nl  = wnh * 32 + j * 16 + fro;
        const int kl  = cc * 32 + fqo * 8;
        bf16x8 o;
#pragma unroll
        for (int e = 0; e < 8; ++e) o[e] = (bf16_t)tld[(kl + e) * 65 + nl];
        *(bf16x8*)&g_whhB[obase + (size_t)b8 * 512 + (size_t)lane_o * 8] = o;
    }
}

// t = 0: h = tanh(x[:,0]*W_hx + b_h); also (re)initialize the counters.
__global__ __launch_bounds__(256) void rnn_init(const float* __restrict__ x,
                                                const float* __restrict__ Whx,
                                                const float* __restrict__ bh) {
    if (blockIdx.x == 0) {
        for (int i = threadIdx.x; i < T_ * 8; i += 256)
            g_cnt[i] = (i < 8) ? 32 : 0;   // g_cnt[0][*] = 32 (h0 ready)
    }
    const int gid = blockIdx.x * 256 + threadIdx.x;
    const int row = gid >> 9;
    const int col = (gid & 511) << 2;
    const float xv = x[(size_t)row * T_];
    f32x4 w = *(const f32x4*)&Whx[col];
    f32x4 b = *(const f32x4*)&bh[col];
    bf16x4 o;
#pragma unroll
    for (int j = 0; j < 4; ++j) o[j] = (bf16_t)tanhf(fmaf(xv, w[j], b[j]));
    *(bf16x4*)&g_hb[0][(size_t)row * H_ + col] = o;
}

// Persistent RNN. v8 = v7 (proven 2192 us: 8 waves 2Mx2Nx2K-parity,
// 6-slot A ring, counted vmcnt, XCD-local rendezvous, zig-zag) with:
//  (1) B never in LDS: fragment-order g_whhB -> coalesced dwordx4 loads
//      (base + lane*16, 1 KB/instr) into a 3-slot VGPR rotation, counted
//      in the SAME in-order vmcnt stream (pair batch = 4 A-DMA + 4 B =
//      8/thread; steady vmcnt(8) = 2-pair lookahead). Deletes 256 KB DMA
//      + 512 KB ds_read per block-step (LDS 2.34 -> 1.57 MB + reduce).
//      v5's B-to-reg failed on stride-H lanes; fragment-order fixes it.
//  (2) K-reduce exchanged in raw fragment layout (f32x4 per lane,
//      contiguous b128, conflict-free) -- kills v7's 1.66e7 bank
//      conflicts and cuts reduce LDS traffic 4x.
__global__ __launch_bounds__(512, 1) void rnn_persist(const float* __restrict__ x,
                                                      const float* __restrict__ Whx,
                                                      const float* __restrict__ bh) {
    extern __shared__ __align__(16) bf16_t smem[];
    bf16_t* As = smem;                 // 6 slots x 8192 elems (16 KB each)
    // reduce scratch aliases As slots 2,3 (computed u13; barrier-protected
    // by u14/u15 waits before the reduce writes).
    float* red = (float*)(As + 2 * 8192);   // 8 waves x 1024 f32 (4 KB each)

    const int tid  = threadIdx.x;
    const int lane = tid & 63;
    const int wave = tid >> 6;                       // 0..7
    const int li  = blockIdx.x;
    const int bm  = li & 7;                          // == XCD (blk%8 map)
    const int bn  = li >> 3;                         // 0..31

    const int wm  = (wave & 1) * 64;                 // M band (64 rows)
    const int wnh = (wave >> 1) & 1;                 // N band idx (32 cols)
    const int wn  = wnh * 32;
    const int kh  = wave >> 2;                       // K parity (chunk&1)
    const int fr = lane & 15, fq = lane >> 4;

    // A staging: linear slot s holds row s>>3, lds-chunk s&7;
    // global chunk = (s&7) ^ (row&7)  (8-row spread -> 2-way frag reads).
    const int rA = tid >> 3;                         // 0..63
    const int cg = (tid & 7) ^ (rA & 7);
    const size_t aofsg = (size_t)(bm * 128 + rA) * H_ + cg * 8;

#define ISSUE_A(SLOT)                                                    \
    do {                                                                 \
        gload16<1>(gpa,           As + (SLOT) * 8192 + tid * 8);         \
        gload16<1>(gpa + 64 * H_, As + (SLOT) * 8192 + (tid + 512) * 8); \
        gpa += kstep;                                                    \
    } while (0)

    // B rotation: 3 slots x [j][cc] bf16x8 = 48 VGPRs, literal-indexed.
    bf16x8 bB[3][2][2];
#define ISSUE_B(BS)                                                      \
    do {                                                                 \
        bB[BS][0][0] = *(const bf16x8*)(gpb + lane * 8);                 \
        bB[BS][0][1] = *(const bf16x8*)(gpb + 512 + lane * 8);           \
        bB[BS][1][0] = *(const bf16x8*)(gpb + 1024 + lane * 8);          \
        bB[BS][1][1] = *(const bf16x8*)(gpb + 1536 + lane * 8);          \
        gpb += bstep;                                                    \
    } while (0)

    // frag offsets (elems): row*64 + ((cc*4+fq) ^ (row&7))*8; row&7 == fr&7.
    const int xr0 = (fq ^ (fr & 7)) * 8;
    const int xr1 = ((4 + fq) ^ (fr & 7)) * 8;
    int aoff[4][2];
#pragma unroll
    for (int i = 0; i < 4; ++i) {
        aoff[i][0] = (wm + i * 16 + fr) * 64 + xr0;
        aoff[i][1] = (wm + i * 16 + fr) * 64 + xr1;
    }

    f32x4 acc[4][2];

#define COMPUTE(SLOT, BS)                                                   \
    {                                                                       \
        _Pragma("unroll")                                                   \
        for (int cc = 0; cc < 2; ++cc) {                                    \
            bf16x8 af[4];                                                   \
            _Pragma("unroll")                                               \
            for (int i = 0; i < 4; ++i)                                     \
                af[i] = *(const bf16x8*)(As + (SLOT) * 8192 + aoff[i][cc]); \
            _Pragma("unroll")                                               \
            for (int i = 0; i < 4; ++i)                                     \
                _Pragma("unroll")                                           \
                for (int j = 0; j < 2; ++j)                                 \
                    acc[i][j] = __builtin_amdgcn_mfma_f32_16x16x32_bf16(    \
                        af[i], bB[BS][j][cc], acc[i][j], 0, 0, 0);          \
        }                                                                   \
    }

    // kh selects which parity's slot this wave computes (wave-uniform).
#define CMP(CE, CO, BS)                                                     \
    do { if (kh == 0) COMPUTE(CE, BS) else COMPUTE(CO, BS) } while (0)

    // per super-iter: stage A pair u+2 (4 vm), load B pair u+2 (4 vm),
    // compute pair u. Steady vmcnt(8) retires exactly pair u's batch.
#define ITER(VM, S1, S2, CE, CO, BI, BC)                                    \
    do { wait_vm_barrier<VM>(); ISSUE_A(S1); ISSUE_A(S2); ISSUE_B(BI);      \
         CMP(CE, CO, BC); } while (0)

    // epilogue constants (step-invariant)
    float wv[2], bv[2];
#pragma unroll
    for (int j = 0; j < 2; ++j) {
        const int col = bn * 64 + wn + j * 16 + fr;
        wv[j] = Whx[col];
        bv[j] = bh[col];
    }

    const bf16_t* const bwave = g_whhB + (size_t)bn * 131072 + (size_t)wnh * 2048;

#pragma unroll 1
    for (int t = 1; t < T_; ++t) {
        const bf16_t* __restrict__ Abuf = g_hb[(t - 1) & 1];
        bf16_t* __restrict__ hn = g_hb[t & 1];
        // zig-zag: odd steps walk K from the top -- L2 still holds that tail
        const int koff  = (t & 1) ? (H_ - 64) : 0;
        const int kstep = (t & 1) ? -64 : 64;
        const int c0b   = (t & 1) ? 31 : 0;
        const int dk    = (t & 1) ? -1 : 1;
        const ptrdiff_t bstep = (ptrdiff_t)dk * 8192;   // 2 chunks
        const bf16_t* gpa = Abuf + aofsg + koff;
        const bf16_t* gpb = bwave + (ptrdiff_t)(c0b + kh * dk) * 4096;

        // B is immutable: load pairs 0,1 into bB BEFORE the dependency wait.
        ISSUE_B(0); ISSUE_B(1);

        // wait until all 32 same-XCD writers of h-rows bm finished step t-1
        if (tid == 0) {
            while (__hip_atomic_load(&g_cnt[(t - 1) * 8 + bm], __ATOMIC_RELAXED,
                                     __HIP_MEMORY_SCOPE_AGENT) != 32)
                __builtin_amdgcn_s_sleep(2);
        }
        // raw barrier: keeps the B prefetch alive (no vmcnt(0) drain);
        // sc0 A-loads read the fresh XCD L2.
        asm volatile("s_barrier" ::: "memory");

        ISSUE_A(0); ISSUE_A(1); ISSUE_A(2); ISSUE_A(3);   // pairs 0,1

#pragma unroll
        for (int i = 0; i < 4; ++i)
#pragma unroll
            for (int j = 0; j < 2; ++j) acc[i][j] = (f32x4)(0.f);

        // queue at u0: [B0(4),B1(4),A0(4),A1(4)] -> vmcnt(4) retires
        // B0,B1,A0; thereafter steady vmcnt(8) retires one pair batch.
        ITER(4, 4, 5, 0, 1, 2, 0);   // u0
        ITER(8, 0, 1, 2, 3, 0, 1);   // u1
        ITER(8, 2, 3, 4, 5, 1, 2);   // u2
        ITER(8, 4, 5, 0, 1, 2, 0);   // u3
        ITER(8, 0, 1, 2, 3, 0, 1);   // u4
        ITER(8, 2, 3, 4, 5, 1, 2);   // u5
        ITER(8, 4, 5, 0, 1, 2, 0);   // u6
        ITER(8, 0, 1, 2, 3, 0, 1);   // u7
        ITER(8, 2, 3, 4, 5, 1, 2);   // u8
        ITER(8, 4, 5, 0, 1, 2, 0);   // u9
        ITER(8, 0, 1, 2, 3, 0, 1);   // u10
        ITER(8, 2, 3, 4, 5, 1, 2);   // u11
        ITER(8, 4, 5, 0, 1, 2, 0);   // u12
        ITER(8, 0, 1, 2, 3, 0, 1);   // u13 (stages pair 15 -> slots 0,1)
        wait_vm_barrier<8>(); CMP(4, 5, 2);   // u14
        wait_vm_barrier<0>(); CMP(0, 1, 0);   // u15

        // ---- cross-wave K-parity reduce (partner = wave^4), raw fragment
        // layout: f32x4 per lane, contiguous b128, conflict-free.
        {
            float* wr = red + wave * 1024;
            if (kh == 0) {
                *(f32x4*)&wr[0 * 256 + lane * 4] = acc[2][0];
                *(f32x4*)&wr[1 * 256 + lane * 4] = acc[2][1];
                *(f32x4*)&wr[2 * 256 + lane * 4] = acc[3][0];
                *(f32x4*)&wr[3 * 256 + lane * 4] = acc[3][1];
            } else {
                *(f32x4*)&wr[0 * 256 + lane * 4] = acc[0][0];
                *(f32x4*)&wr[1 * 256 + lane * 4] = acc[0][1];
                *(f32x4*)&wr[2 * 256 + lane * 4] = acc[1][0];
                *(f32x4*)&wr[3 * 256 + lane * 4] = acc[1][1];
            }
        }
        __syncthreads();
        {
            const float* rd = red + (wave ^ 4) * 1024;
            if (kh == 0) {
                acc[0][0] += *(const f32x4*)&rd[0 * 256 + lane * 4];
                acc[0][1] += *(const f32x4*)&rd[1 * 256 + lane * 4];
                acc[1][0] += *(const f32x4*)&rd[2 * 256 + lane * 4];
                acc[1][1] += *(const f32x4*)&rd[3 * 256 + lane * 4];
            } else {
                acc[2][0] += *(const f32x4*)&rd[0 * 256 + lane * 4];
                acc[2][1] += *(const f32x4*)&rd[1 * 256 + lane * 4];
                acc[3][0] += *(const f32x4*)&rd[2 * 256 + lane * 4];
                acc[3][1] += *(const f32x4*)&rd[3 * 256 + lane * 4];
            }
        }

        // epilogue: + x_t*W_hx + b_h, tanh, bf16 store (kept half only)
#define EPI(I)                                                              \
        {                                                                   \
            const int row0 = bm * 128 + wm + (I) * 16 + fq * 4;             \
            float xv[4];                                                    \
            _Pragma("unroll")                                               \
            for (int r = 0; r < 4; ++r) xv[r] = x[(row0 + r) * T_ + t];     \
            _Pragma("unroll")                                               \
            for (int j = 0; j < 2; ++j) {                                   \
                const int col = bn * 64 + wn + j * 16 + fr;                 \
                _Pragma("unroll")                                           \
                for (int r = 0; r < 4; ++r)                                 \
                    hn[(size_t)(row0 + r) * H_ + col] =                     \
                        (bf16_t)tanhf(acc[I][j][r] + xv[r] * wv[j] + bv[j]);\
            }                                                               \
        }
        if (kh == 0) { EPI(0) EPI(1) } else { EPI(2) EPI(3) }
#undef EPI

        // publish: drain this wave's stores to L2, join waves, bump counter.
        asm volatile("s_waitcnt vmcnt(0)" ::: "memory");
        __syncthreads();
        if (tid == 0)
            __hip_atomic_fetch_add(&g_cnt[t * 8 + bm], 1, __ATOMIC_RELAXED,
                                   __HIP_MEMORY_SCOPE_AGENT);
    }
#undef ITER
#undef CMP
#undef COMPUTE
#undef ISSUE_B
#undef ISSUE_A
}

// p = h_T @ W_ph + b_p : one wave per batch row, fp32 accumulate.
__global__ __launch_bounds__(64) void rnn_proj(const float* __restrict__ Wph,
                                               const float* __restrict__ bp,
                                               float* __restrict__ out, int sb) {
    const int b = blockIdx.x;
    const int l = threadIdx.x;
    const bf16_t* h = g_hb[sb] + (size_t)b * H_;
    float acc[C_];
#pragma unroll
    for (int c = 0; c < C_; ++c) acc[c] = 0.f;
    for (int k = l; k < H_; k += 64) {
        const float hv = (float)h[k];
#pragma unroll
        for (int c = 0; c < C_; ++c)
            acc[c] = fmaf(hv, Wph[k * C_ + c], acc[c]);
    }
#pragma unroll
    for (int off = 32; off > 0; off >>= 1)
#pragma unroll
        for (int c = 0; c < C_; ++c) acc[c] += __shfl_down(acc[c], off);
    if (l == 0) {
#pragma unroll
        for (int c = 0; c < C_; ++c) out[b * C_ + c] = acc[c] + bp[c];
    }
}

extern "C" void kernel_launch(void* const* d_in, const int* in_sizes, int n_in,
                              void* d_out, int out_size, void* d_ws, size_t ws_size,
                              hipStream_t stream) {
    const float* x   = (const float*)d_in[0];   // [1024,128]
    const float* Whx = (const float*)d_in[1];   // [1,2048]
    const float* Whh = (const float*)d_in[2];   // [2048,2048]
    const float* bh  = (const float*)d_in[3];   // [2048]
    const float* Wph = (const float*)d_in[4];   // [2048,10]
    const float* bp  = (const float*)d_in[5];   // [1,10]
    float* out = (float*)d_out;                 // [1024,10]

    static bool attr_set = false;
    if (!attr_set) {
        hipFuncSetAttribute((const void*)rnn_persist,
                            hipFuncAttributeMaxDynamicSharedMemorySize, 98304);
        attr_set = true;
    }

    prep_whhB<<<dim3(32, 32), 256, 0, stream>>>(Whh);
    rnn_init<<<(B_ * H_ / 4) / 256, 256, 0, stream>>>(x, Whx, bh);
    rnn_persist<<<256, 512, 98304, stream>>>(x, Whx, bh);
    rnn_proj<<<B_, 64, 0, stream>>>(Wph, bp, out, (T_ - 1) & 1);
}